// Round 1
// baseline (1377.118 us; speedup 1.0000x reference)
//
#include <hip/hip_runtime.h>

typedef unsigned short u16;
typedef float  f32x4  __attribute__((ext_vector_type(4)));
typedef short  bf16x8 __attribute__((ext_vector_type(8)));
typedef u16    u16x8  __attribute__((ext_vector_type(8)));
typedef float  f32x4v __attribute__((ext_vector_type(4)));

#define BROWS 32768
#define KTOT  3584
#define BM 128
#define BN 128
#define BK 32

static __device__ __forceinline__ u16 f2b(float f) {
    unsigned x = __float_as_uint(f);
    x += 0x7fffu + ((x >> 16) & 1u);        // round-to-nearest-even
    return (u16)(x >> 16);
}
static __device__ __forceinline__ float b2f(u16 u) {
    return __uint_as_float(((unsigned)u) << 16);
}
static __device__ __forceinline__ float sigm(float x) {
    return 1.f / (1.f + __expf(-x));
}
static __device__ __forceinline__ float tanh_s(float x) {
    float ax = fabsf(x);
    float e  = __expf(-2.f * ax);
    float t  = (1.f - e) / (1.f + e);
    return copysignf(t, x);
}
static __device__ __forceinline__ void gld16(const u16* g, u16* l) {
    __builtin_amdgcn_global_load_lds(
        (const __attribute__((address_space(1))) void*)g,
        (__attribute__((address_space(3))) void*)l, 16, 0, 0);
}

// ---------------------------------------------------------------------------
// pack_x: Xcat[b][0:512]=bf16(emb[y[b]]), [512:1536]=bf16(s[b]), [1536:3584]=bf16(c[b])
// one thread handles 8 consecutive elements
// ---------------------------------------------------------------------------
__global__ __launch_bounds__(256) void pack_x(
    const float* __restrict__ s, const int* __restrict__ y,
    const float* __restrict__ c, const float* __restrict__ emb,
    u16* __restrict__ X)
{
    long tid = (long)blockIdx.x * 256 + threadIdx.x;   // B*448 threads
    int  row = (int)(tid / 448);
    int  seg = (int)(tid % 448);
    int  e0  = seg * 8;
    const float* src;
    if (e0 < 512)        src = emb + (long)y[row] * 512 + e0;
    else if (e0 < 1536)  src = s   + (long)row * 1024 + (e0 - 512);
    else                 src = c   + (long)row * 2048 + (e0 - 1536);
    f32x4 a = *(const f32x4*)src;
    f32x4 b = *(const f32x4*)(src + 4);
    u16x8 o;
    o[0]=f2b(a[0]); o[1]=f2b(a[1]); o[2]=f2b(a[2]); o[3]=f2b(a[3]);
    o[4]=f2b(b[0]); o[5]=f2b(b[1]); o[6]=f2b(b[2]); o[7]=f2b(b[3]);
    *(u16x8*)&X[(long)row * KTOT + e0] = o;
}

// ---------------------------------------------------------------------------
// wtrans: dst[n*ldd + k] = bf16(src[k*1024 + n])  (K x 1024 -> transposed slab)
// ---------------------------------------------------------------------------
__global__ __launch_bounds__(256) void wtrans(
    const float* __restrict__ src, u16* __restrict__ dst, int ldd)
{
    __shared__ float t[32][33];
    int k0 = blockIdx.x * 32, n0 = blockIdx.y * 32;
    int tx = threadIdx.x, ty = threadIdx.y;
    #pragma unroll
    for (int r = ty; r < 32; r += 8)
        t[r][tx] = src[(long)(k0 + r) * 1024 + n0 + tx];
    __syncthreads();
    #pragma unroll
    for (int r = ty; r < 32; r += 8)
        dst[(long)(n0 + r) * ldd + k0 + tx] = f2b(t[tx][r]);
}

// ---------------------------------------------------------------------------
// Fused GEMM (m97 structure): 128x128 tile, BK=32, 4 waves, 16x16x32 bf16 MFMA
// MODE 0: A=Xcat (B x 3584), Wt=WzrT (2048 x 3584)
//         epilogue: col<1024 -> zbuf = bf16(sigm(acc))
//                   col>=1024 -> rsbuf = bf16(sigm(acc) * s)
// MODE 1: A=[Xcat.y | rs | Xcat.c], Wt=W2T (1024 x 3584)
//         epilogue: out = s + z*(tanh(acc) - s)
// ---------------------------------------------------------------------------
template<int MODE>
__global__ __launch_bounds__(256) void gemm_fused(
    const u16* __restrict__ Xc, const u16* __restrict__ rsin,
    const u16* __restrict__ Wt, const float* __restrict__ sprev,
    u16* __restrict__ zb, u16* __restrict__ rsb,
    const u16* __restrict__ zread, float* __restrict__ out, int NT)
{
    __shared__ u16 As[BM * BK];
    __shared__ u16 Bs[BN * BK];

    int bid = blockIdx.x;
    int nwg = gridDim.x;
    int q   = nwg >> 3;                       // nwg divisible by 8
    int wg  = (bid & 7) * q + (bid >> 3);     // XCD-contiguous swizzle
    int bm  = wg / NT, bn = wg % NT;
    long brow = (long)bm * BM;
    int  bcol = bn * BN;

    int t = threadIdx.x, w = t >> 6, l = t & 63;
    int wr = w >> 1, wc = w & 1;

    f32x4 acc[4][4];
    #pragma unroll
    for (int m = 0; m < 4; m++)
        #pragma unroll
        for (int n = 0; n < 4; n++)
            acc[m][n] = (f32x4){0.f, 0.f, 0.f, 0.f};

    int rA0 = w * 16 + (l >> 2);   // staging row within tile (+i*64)
    int kA0 = (l & 3) * 8;         // staging k-offset (elements)
    u16* ldsA0 = As + w * 512;     // uniform per-wave dest (+i*2048)
    u16* ldsB0 = Bs + w * 512;
    const u16* Brow = Wt + (long)bcol * KTOT;

    for (int k0 = 0; k0 < KTOT; k0 += BK) {
        const u16* abase; long lda; int kc;
        if (MODE == 0) { abase = Xc; lda = KTOT; kc = k0; }
        else {
            if (k0 < 512)       { abase = Xc;   lda = KTOT; kc = k0; }
            else if (k0 < 1536) { abase = rsin; lda = 1024; kc = k0 - 512; }
            else                { abase = Xc;   lda = KTOT; kc = k0; }
        }
        #pragma unroll
        for (int i = 0; i < 2; i++)
            gld16(abase + (brow + rA0 + i * 64) * lda + kc + kA0,
                  ldsA0 + i * 2048);
        #pragma unroll
        for (int i = 0; i < 2; i++)
            gld16(Brow + (long)(rA0 + i * 64) * KTOT + k0 + kA0,
                  ldsB0 + i * 2048);

        __syncthreads();   // drains vmcnt before barrier

        bf16x8 af[4], bfr[4];
        #pragma unroll
        for (int m = 0; m < 4; m++)
            af[m] = *(const bf16x8*)&As[(wr * 64 + m * 16 + (l & 15)) * BK + (l >> 4) * 8];
        #pragma unroll
        for (int n = 0; n < 4; n++)
            bfr[n] = *(const bf16x8*)&Bs[(wc * 64 + n * 16 + (l & 15)) * BK + (l >> 4) * 8];

        #pragma unroll
        for (int m = 0; m < 4; m++)
            #pragma unroll
            for (int n = 0; n < 4; n++)
                acc[m][n] = __builtin_amdgcn_mfma_f32_16x16x32_bf16(
                    af[m], bfr[n], acc[m][n], 0, 0, 0);

        __syncthreads();
    }

    // epilogue: C/D layout col=lane&15, row=(lane>>4)*4+j
    int lrow = (l >> 4) * 4, lcol = l & 15;
    #pragma unroll
    for (int m = 0; m < 4; m++) {
        long row0 = brow + wr * 64 + m * 16 + lrow;
        #pragma unroll
        for (int n = 0; n < 4; n++) {
            int col = bcol + wc * 64 + n * 16 + lcol;
            #pragma unroll
            for (int j = 0; j < 4; j++) {
                float v = acc[m][n][j];
                long r = row0 + j;
                if (MODE == 0) {
                    if (col < 1024) {
                        zb[r * 1024 + col] = f2b(sigm(v));
                    } else {
                        int h = col - 1024;
                        float rr = sigm(v);
                        rsb[r * 1024 + h] = f2b(rr * sprev[r * 1024 + h]);
                    }
                } else {
                    float st = tanh_s(v);
                    float z  = b2f(zread[r * 1024 + col]);
                    float sv = sprev[r * 1024 + col];
                    out[r * 1024 + col] = fmaf(z, st - sv, sv);
                }
            }
        }
    }
}

// ---------------------------------------------------------------------------
extern "C" void kernel_launch(void* const* d_in, const int* in_sizes, int n_in,
                              void* d_out, int out_size, void* d_ws, size_t ws_size,
                              hipStream_t stream)
{
    const float* s   = (const float*)d_in[0];
    const int*   y   = (const int*)  d_in[1];
    const float* c   = (const float*)d_in[2];
    const float* emb = (const float*)d_in[3];
    const float* Wz  = (const float*)d_in[4];
    const float* Uz  = (const float*)d_in[5];
    const float* Cz  = (const float*)d_in[6];
    const float* Wr  = (const float*)d_in[7];
    const float* Ur  = (const float*)d_in[8];
    const float* Cr  = (const float*)d_in[9];
    const float* W   = (const float*)d_in[10];
    const float* U   = (const float*)d_in[11];
    const float* C   = (const float*)d_in[12];
    float* out = (float*)d_out;

    char* ws = (char*)d_ws;
    u16* Xcat = (u16*)(ws);                                  // B*3584*2 = 234881024
    u16* rsb  = (u16*)(ws + 234881024);                      // B*1024*2 =  67108864
    u16* zbuf = (u16*)(ws + 301989888);                      // B*1024*2 =  67108864
    u16* WzrT = (u16*)(ws + 369098752);                      // 2048*3584*2 = 14680064
    u16* W2T  = (u16*)(ws + 383778816);                      // 1024*3584*2 =  7340032
    // total 391118848 bytes

    // pack activations
    pack_x<<<BROWS * 448 / 256, 256, 0, stream>>>(s, y, c, emb, Xcat);

    // pack + transpose weights into [N x 3584] bf16 slabs
    dim3 tb(32, 8);
    wtrans<<<dim3(16, 32), tb, 0, stream>>>(Wz, WzrT + 0,                 KTOT);
    wtrans<<<dim3(32, 32), tb, 0, stream>>>(Uz, WzrT + 512,               KTOT);
    wtrans<<<dim3(64, 32), tb, 0, stream>>>(Cz, WzrT + 1536,              KTOT);
    wtrans<<<dim3(16, 32), tb, 0, stream>>>(Wr, WzrT + 1024 * KTOT,       KTOT);
    wtrans<<<dim3(32, 32), tb, 0, stream>>>(Ur, WzrT + 1024 * KTOT + 512, KTOT);
    wtrans<<<dim3(64, 32), tb, 0, stream>>>(Cr, WzrT + 1024 * KTOT + 1536,KTOT);
    wtrans<<<dim3(16, 32), tb, 0, stream>>>(W,  W2T + 0,                  KTOT);
    wtrans<<<dim3(32, 32), tb, 0, stream>>>(U,  W2T + 512,                KTOT);
    wtrans<<<dim3(64, 32), tb, 0, stream>>>(C,  W2T + 1536,               KTOT);

    // GEMM1: (B x 3584) @ (3584 x 2048) -> z, rs
    gemm_fused<0><<<(BROWS / BM) * (2048 / BN), 256, 0, stream>>>(
        Xcat, nullptr, WzrT, s, zbuf, rsb, nullptr, nullptr, 2048 / BN);

    // GEMM2: ([y|rs|c] B x 3584) @ (3584 x 1024) -> out
    gemm_fused<1><<<(BROWS / BM) * (1024 / BN), 256, 0, stream>>>(
        Xcat, rsb, W2T, s, nullptr, nullptr, zbuf, out, 1024 / BN);
}

// Round 2
// 1016.477 us; speedup vs baseline: 1.3548x; 1.3548x over previous
//
#include <hip/hip_runtime.h>

typedef unsigned short u16;
typedef float  f32x4  __attribute__((ext_vector_type(4)));
typedef short  bf16x8 __attribute__((ext_vector_type(8)));
typedef u16    u16x8  __attribute__((ext_vector_type(8)));

#define BROWS 32768
#define KTOT  3584
#define NKT   (KTOT / 64)

static __device__ __forceinline__ u16 f2b(float f) {
    unsigned x = __float_as_uint(f);
    x += 0x7fffu + ((x >> 16) & 1u);        // round-to-nearest-even
    return (u16)(x >> 16);
}
static __device__ __forceinline__ float b2f(u16 u) {
    return __uint_as_float(((unsigned)u) << 16);
}
static __device__ __forceinline__ float sigm(float x) {
    return 1.f / (1.f + __expf(-x));
}
static __device__ __forceinline__ float tanh_s(float x) {
    float ax = fabsf(x);
    float e  = __expf(-2.f * ax);
    float t  = (1.f - e) / (1.f + e);
    return copysignf(t, x);
}
static __device__ __forceinline__ void gld16(const u16* g, u16* l) {
    __builtin_amdgcn_global_load_lds(
        (const __attribute__((address_space(1))) void*)g,
        (__attribute__((address_space(3))) void*)l, 16, 0, 0);
}

// ---------------------------------------------------------------------------
// pack_x: Xcat[b] = [bf16(emb[y[b]]) | bf16(s[b]) | bf16(c[b])]   (B x 3584)
// ---------------------------------------------------------------------------
__global__ __launch_bounds__(256) void pack_x(
    const float* __restrict__ s, const int* __restrict__ y,
    const float* __restrict__ c, const float* __restrict__ emb,
    u16* __restrict__ X)
{
    long tid = (long)blockIdx.x * 256 + threadIdx.x;   // B*448 threads
    int  row = (int)(tid / 448);
    int  seg = (int)(tid % 448);
    int  e0  = seg * 8;
    const float* src;
    if (e0 < 512)        src = emb + (long)y[row] * 512 + e0;
    else if (e0 < 1536)  src = s   + (long)row * 1024 + (e0 - 512);
    else                 src = c   + (long)row * 2048 + (e0 - 1536);
    f32x4 a = *(const f32x4*)src;
    f32x4 b = *(const f32x4*)(src + 4);
    u16x8 o;
    o[0]=f2b(a[0]); o[1]=f2b(a[1]); o[2]=f2b(a[2]); o[3]=f2b(a[3]);
    o[4]=f2b(b[0]); o[5]=f2b(b[1]); o[6]=f2b(b[2]); o[7]=f2b(b[3]);
    *(u16x8*)&X[(long)row * KTOT + e0] = o;
}

// ---------------------------------------------------------------------------
// wtrans: dst[n*ldd + k] = bf16(src[k*1024 + n])
// ---------------------------------------------------------------------------
__global__ __launch_bounds__(256) void wtrans(
    const float* __restrict__ src, u16* __restrict__ dst, int ldd)
{
    __shared__ float t[32][33];
    int k0 = blockIdx.x * 32, n0 = blockIdx.y * 32;
    int tx = threadIdx.x, ty = threadIdx.y;
    #pragma unroll
    for (int r = ty; r < 32; r += 8)
        t[r][tx] = src[(long)(k0 + r) * 1024 + n0 + tx];
    __syncthreads();
    #pragma unroll
    for (int r = ty; r < 32; r += 8)
        dst[(long)(n0 + r) * ldd + k0 + tx] = f2b(t[tx][r]);
}

// ---------------------------------------------------------------------------
// 256x256x64 8-wave 4-phase GEMM (T2 swizzle + T3/T4 counted vmcnt + T5 prio)
// LDS per buffer (u16 units): A half0 [8192] | A half1 [8192] | B half0 | B half1
// Subtile = 16 rows x 32 cols bf16 = 1024B, st_16x32 swizzle:
//   lds_u16(row,col) = st*512 + (row&15)*32 + ((col&31) ^ (((row>>3)&1)*16))
// Staged via linear global_load_lds with inverse-swizzled GLOBAL source.
// ---------------------------------------------------------------------------

#define RDA(m,ks)  a[m][ks]  = *(const bf16x8*)(Ab  + (m)*1024 + (ks)*512 + lane_off)
#define RDB(n,ks)  bb[n][ks] = *(const bf16x8*)(Bb2 + (n)*1024 + (ks)*512 + lane_off)
#define RDA4(m0)   RDA(m0,0);RDA(m0,1);RDA(m0+1,0);RDA(m0+1,1);RDA(m0+2,0);RDA(m0+2,1);RDA(m0+3,0);RDA(m0+3,1)
#define RDB2(n0)   RDB(n0,0);RDB(n0,1);RDB(n0+1,0);RDB(n0+1,1)
#define MM1(m,n,ks) acc[m][n] = __builtin_amdgcn_mfma_f32_16x16x32_bf16(a[m][ks], bb[n][ks], acc[m][n], 0, 0, 0)
#define MMROW(m,n0) MM1(m,n0,0); MM1(m,n0,1); MM1(m,n0+1,0); MM1(m,n0+1,1)
#define MMQUAD(m0,n0) MMROW(m0,n0); MMROW(m0+1,n0); MMROW(m0+2,n0); MMROW(m0+3,n0)

#define PHASE_SYNC \
    __builtin_amdgcn_s_barrier(); \
    asm volatile("s_waitcnt lgkmcnt(0)" ::: "memory"); \
    __builtin_amdgcn_sched_barrier(0); \
    __builtin_amdgcn_s_setprio(1);

#define PHASE_END \
    __builtin_amdgcn_s_setprio(0); \
    __builtin_amdgcn_sched_barrier(0); \
    __builtin_amdgcn_s_barrier();

template<int MODE>
__global__ __launch_bounds__(512, 2) void gemm8(
    const u16* __restrict__ Xc, const u16* __restrict__ rsin,
    const u16* __restrict__ Wt, const float* __restrict__ sprev,
    u16* __restrict__ zb, u16* __restrict__ rsb,
    const u16* __restrict__ zread, float* __restrict__ out, int NT)
{
    extern __shared__ u16 smem[];   // 2 x 32768 u16 = 128 KiB

    int bid = blockIdx.x, nwg = gridDim.x;
    int q   = nwg >> 3;                        // nwg divisible by 8
    int wg  = (bid & 7) * q + (bid >> 3);      // XCD-contiguous swizzle
    int bm  = wg / NT, bn = wg % NT;
    int R0  = bm * 256;
    int C0  = bn * 256;

    int t = threadIdx.x, w = t >> 6, l = t & 63;
    int wr = w >> 2, wc = w & 3;               // 2 x 4 wave grid

    // ---- staging constants (inverse-swizzled global source) ----
    int rl   = l >> 2;                               // subtile row 0..15
    int ccl  = ((l & 3) * 8) ^ ((l >> 5) * 16);      // subtile col (elements)
    int sr0  = w >> 1, sc = w & 1;
    int colb = sc * 32 + ccl;
    int offAx[2][2], offAr[2][2], offB[2][2];
    #pragma unroll
    for (int h = 0; h < 2; h++)
        #pragma unroll
        for (int i = 0; i < 2; i++) {
            int row = h * 128 + (sr0 + i * 4) * 16 + rl;
            offAx[h][i] = (R0 + row) * KTOT + colb;
            offAr[h][i] = (R0 + row) * 1024 + colb - 512;   // rs segment (MODE 1)
            offB [h][i] = (C0 + row) * KTOT + colb;
        }

    auto stage = [&](int kt) {
        int bs = kt & 1;
        int k0 = kt * 64;
        u16* Ld = smem + bs * 32768;
        bool useR = (MODE == 1) && (k0 >= 512) && (k0 < 1536);
        #pragma unroll
        for (int h = 0; h < 2; h++)
            #pragma unroll
            for (int i = 0; i < 2; i++) {
                const u16* g = useR ? (rsin + (offAr[h][i] + k0))
                                    : (Xc   + (offAx[h][i] + k0));
                gld16(g, Ld + h * 8192 + (w + i * 8) * 512);
            }
        #pragma unroll
        for (int h = 0; h < 2; h++)
            #pragma unroll
            for (int i = 0; i < 2; i++)
                gld16(Wt + (offB[h][i] + k0),
                      Ld + 16384 + h * 8192 + (w + i * 8) * 512);
    };

    // ---- read-side swizzled lane offset (u16 units) ----
    int lane_off = (l & 15) * 32 + (((l >> 4) * 8) ^ (((l >> 3) & 1) * 16));

    f32x4 acc[8][4];
    #pragma unroll
    for (int m = 0; m < 8; m++)
        #pragma unroll
        for (int n = 0; n < 4; n++)
            acc[m][n] = (f32x4){0.f, 0.f, 0.f, 0.f};

    bf16x8 a[8][2], bb[4][2];

    // ---- prologue: stage tiles 0 and 1 ----
    stage(0);
    stage(1);
    asm volatile("s_waitcnt vmcnt(8)" ::: "memory");   // tile 0 landed
    __builtin_amdgcn_s_barrier();

    for (int kt = 0; kt < NKT; ++kt) {
        int bs = kt & 1;
        const u16* Ab  = smem + bs * 32768 + wr * 8192;
        const u16* Bb2 = smem + bs * 32768 + 16384 + (wc >> 1) * 8192 + (wc & 1) * 4096;

        // phase 0: quadrant (m0-3, n0-1)
        RDA4(0); RDB2(0);
        PHASE_SYNC; MMQUAD(0, 0); PHASE_END;
        // phase 1: quadrant (m0-3, n2-3)
        RDB2(2);
        PHASE_SYNC; MMQUAD(0, 2); PHASE_END;
        // phase 2: quadrant (m4-7, n2-3)
        RDA4(4);
        PHASE_SYNC; MMQUAD(4, 2); PHASE_END;
        // phase 3: stage tile kt+2 into this (now fully-read) buffer,
        // certify tile kt+1 with counted vmcnt, compute (m4-7, n0-1) from regs
        if (kt + 2 < NKT) {
            stage(kt + 2);
            asm volatile("s_waitcnt vmcnt(8)" ::: "memory");
        } else {
            asm volatile("s_waitcnt vmcnt(0)" ::: "memory");
        }
        __builtin_amdgcn_sched_barrier(0);
        __builtin_amdgcn_s_barrier();
        __builtin_amdgcn_s_setprio(1);
        MMQUAD(4, 0);
        PHASE_END;
    }

    // ---- epilogue: C/D layout col=lane&15, row=(lane>>4)*4+j ----
    int lr = (l >> 4) * 4, lc = l & 15;
    long R0w = R0 + wr * 128;
    int  C0w = C0 + wc * 64;
    if (MODE == 0) {
        if (C0 < 1024) {                       // whole tile in z region
            #pragma unroll
            for (int m = 0; m < 8; m++)
                #pragma unroll
                for (int n = 0; n < 4; n++) {
                    int col = C0w + n * 16 + lc;
                    #pragma unroll
                    for (int j = 0; j < 4; j++) {
                        long r = R0w + m * 16 + lr + j;
                        zb[r * 1024 + col] = f2b(sigm(acc[m][n][j]));
                    }
                }
        } else {                               // whole tile in r region
            #pragma unroll
            for (int m = 0; m < 8; m++)
                #pragma unroll
                for (int n = 0; n < 4; n++) {
                    int h = C0w + n * 16 + lc - 1024;
                    #pragma unroll
                    for (int j = 0; j < 4; j++) {
                        long r = R0w + m * 16 + lr + j;
                        float rr = sigm(acc[m][n][j]);
                        rsb[r * 1024 + h] = f2b(rr * sprev[r * 1024 + h]);
                    }
                }
        }
    } else {
        #pragma unroll
        for (int m = 0; m < 8; m++)
            #pragma unroll
            for (int n = 0; n < 4; n++) {
                int col = C0w + n * 16 + lc;
                #pragma unroll
                for (int j = 0; j < 4; j++) {
                    long r = R0w + m * 16 + lr + j;
                    float st = tanh_s(acc[m][n][j]);
                    float z  = b2f(zread[r * 1024 + col]);
                    float sv = sprev[r * 1024 + col];
                    out[r * 1024 + col] = fmaf(z, st - sv, sv);
                }
            }
    }
}

// ---------------------------------------------------------------------------
extern "C" void kernel_launch(void* const* d_in, const int* in_sizes, int n_in,
                              void* d_out, int out_size, void* d_ws, size_t ws_size,
                              hipStream_t stream)
{
    const float* s   = (const float*)d_in[0];
    const int*   y   = (const int*)  d_in[1];
    const float* c   = (const float*)d_in[2];
    const float* emb = (const float*)d_in[3];
    const float* Wz  = (const float*)d_in[4];
    const float* Uz  = (const float*)d_in[5];
    const float* Cz  = (const float*)d_in[6];
    const float* Wr  = (const float*)d_in[7];
    const float* Ur  = (const float*)d_in[8];
    const float* Cr  = (const float*)d_in[9];
    const float* W   = (const float*)d_in[10];
    const float* U   = (const float*)d_in[11];
    const float* C   = (const float*)d_in[12];
    float* out = (float*)d_out;

    char* ws = (char*)d_ws;
    u16* Xcat = (u16*)(ws);                                  // B*3584*2
    u16* rsb  = (u16*)(ws + 234881024);                      // B*1024*2
    u16* zbuf = (u16*)(ws + 301989888);                      // B*1024*2
    u16* WzrT = (u16*)(ws + 369098752);                      // 2048*3584*2
    u16* W2T  = (u16*)(ws + 383778816);                      // 1024*3584*2

    hipFuncSetAttribute((const void*)gemm8<0>,
                        hipFuncAttributeMaxDynamicSharedMemorySize, 131072);
    hipFuncSetAttribute((const void*)gemm8<1>,
                        hipFuncAttributeMaxDynamicSharedMemorySize, 131072);

    pack_x<<<BROWS * 448 / 256, 256, 0, stream>>>(s, y, c, emb, Xcat);

    dim3 tb(32, 8);
    wtrans<<<dim3(16, 32), tb, 0, stream>>>(Wz, WzrT + 0,                 KTOT);
    wtrans<<<dim3(32, 32), tb, 0, stream>>>(Uz, WzrT + 512,               KTOT);
    wtrans<<<dim3(64, 32), tb, 0, stream>>>(Cz, WzrT + 1536,              KTOT);
    wtrans<<<dim3(16, 32), tb, 0, stream>>>(Wr, WzrT + 1024 * KTOT,       KTOT);
    wtrans<<<dim3(32, 32), tb, 0, stream>>>(Ur, WzrT + 1024 * KTOT + 512, KTOT);
    wtrans<<<dim3(64, 32), tb, 0, stream>>>(Cr, WzrT + 1024 * KTOT + 1536,KTOT);
    wtrans<<<dim3(16, 32), tb, 0, stream>>>(W,  W2T + 0,                  KTOT);
    wtrans<<<dim3(32, 32), tb, 0, stream>>>(U,  W2T + 512,                KTOT);
    wtrans<<<dim3(64, 32), tb, 0, stream>>>(C,  W2T + 1536,               KTOT);

    // GEMM1: (B x 3584) @ (3584 x 2048) -> z, rs   (128 x 8 = 1024 wgs)
    gemm8<0><<<(BROWS / 256) * (2048 / 256), 512, 131072, stream>>>(
        Xcat, nullptr, WzrT, s, zbuf, rsb, nullptr, nullptr, 2048 / 256);

    // GEMM2: ([y|rs|c] B x 3584) @ (3584 x 1024) -> out   (128 x 4 = 512 wgs)
    gemm8<1><<<(BROWS / 256) * (1024 / 256), 512, 131072, stream>>>(
        Xcat, rsb, W2T, s, nullptr, nullptr, zbuf, out, 1024 / 256);
}